// Round 1
// 383.157 us; speedup vs baseline: 1.0218x; 1.0218x over previous
//
#include <hip/hip_runtime.h>
#include <math.h>

#define B 32
#define C 512
#define H 56
#define W 56
#define HW (H * W)      // 3136
#define HW4 (HW / 4)    // 784
#define KD 768

#define BAND 4                // output rows per fused block
#define NBAND (H / BAND)      // 14
#define CG 64                 // channels per fused block
#define NCG (C / CG)          // 8
#define HROWS (BAND + 6)      // 10 halo rows
#define HCOLS (W + 6)         // 62 halo cols

typedef float floatx4 __attribute__((ext_vector_type(4)));

// ---------------- Kernel 1: channel-wise max + mean pooling ----------------
// (unchanged from previous verified version)
// Block: 512 threads = 32 float4-positions x 16 channel-groups (32 ch each).
// Grid 784 blocks -> ~24 waves/CU for latency hiding.
__global__ __launch_bounds__(512) void pool_kernel(
    const float* __restrict__ x, float* __restrict__ cmax, float* __restrict__ cmean) {
    const int tid = threadIdx.x;
    const int pos = tid & 31;          // 0..31
    const int cg  = tid >> 5;          // 0..15
    const int p   = blockIdx.x * 32 + pos;   // float4 position in [0, B*HW4)
    const int b   = p / HW4;
    const int hw4 = p - b * HW4;

    const floatx4* xb = (const floatx4*)x + (size_t)b * C * HW4 + hw4;

    floatx4 mx = { -INFINITY, -INFINITY, -INFINITY, -INFINITY };
    floatx4 sm = { 0.f, 0.f, 0.f, 0.f };
    const int c0 = cg * 32;
    #pragma unroll 4
    for (int c = c0; c < c0 + 32; ++c) {
        floatx4 v = xb[(size_t)c * HW4];
        mx.x = fmaxf(mx.x, v.x); mx.y = fmaxf(mx.y, v.y);
        mx.z = fmaxf(mx.z, v.z); mx.w = fmaxf(mx.w, v.w);
        sm += v;
    }

    __shared__ floatx4 smax[16][32];
    __shared__ floatx4 ssum[16][32];
    smax[cg][pos] = mx;
    ssum[cg][pos] = sm;
    __syncthreads();

    if (tid < 32) {
        mx = smax[0][tid];
        sm = ssum[0][tid];
        #pragma unroll
        for (int g = 1; g < 16; ++g) {
            floatx4 m2 = smax[g][tid];
            mx.x = fmaxf(mx.x, m2.x); mx.y = fmaxf(mx.y, m2.y);
            mx.z = fmaxf(mx.z, m2.z); mx.w = fmaxf(mx.w, m2.w);
            sm += ssum[g][tid];
        }
        const float inv = 1.0f / (float)C;
        floatx4 mn = sm * inv;
        const int pp = blockIdx.x * 32 + tid;
        ((floatx4*)cmax)[pp]  = mx;
        ((floatx4*)cmean)[pp] = mn;
    }
}

// ---------------- Kernel 2: fused bias + 7x7 conv + sigmoid + x*scale ----------------
// Block = (b, 4-row band, 64-channel group). Per block:
//   A) stage conv weights + zero-padded 10x62 halo of cmax/cmean in LDS,
//      redundantly compute keyword bias (768 FMA) via wave reduce;
//   B) 224 threads compute conv+sigmoid -> s_scale[224] in LDS;
//   C) stream 64 channels x 56 float4 of x: out = x * scale (NT load/store).
// Conv recompute redundancy is 8x (once per channel group) ~ 157 MFLOP total: noise.
__global__ __launch_bounds__(256) void fused_kernel(
    const float* __restrict__ cmax, const float* __restrict__ cmean,
    const float* __restrict__ conv_w, const float* __restrict__ conv_b,
    const float* __restrict__ keyword, const float* __restrict__ proj_w,
    const float* __restrict__ proj_b,
    const floatx4* __restrict__ x4, floatx4* __restrict__ out4) {
    __shared__ float sm[2][HROWS][HCOLS];          // 4960 B, zero-padded halos
    __shared__ float s_w[98];                      // conv weights (max | mean)
    __shared__ __align__(16) float s_scale[BAND * W];  // 224 sigmoid scales
    __shared__ float s_red[4];                     // per-wave bias partials

    const int tid  = threadIdx.x;
    const int bid  = blockIdx.x;
    const int cg   = bid & (NCG - 1);              // 0..7, fastest
    const int rest = bid >> 3;                     // b*14 + band
    const int band = rest % NBAND;
    const int b    = rest / NBAND;
    const int row0 = band * BAND;

    // --- Phase A ---
    if (tid < 98) s_w[tid] = conv_w[tid];

    // keyword bias partial: dot(keyword[b,:], proj_w) over 768 = 3 terms/thread
    float part = keyword[b * KD + tid]       * proj_w[tid]
               + keyword[b * KD + tid + 256] * proj_w[tid + 256]
               + keyword[b * KD + tid + 512] * proj_w[tid + 512];
    #pragma unroll
    for (int off = 32; off > 0; off >>= 1)
        part += __shfl_down(part, off);
    if ((tid & 63) == 0) s_red[tid >> 6] = part;

    // zero-padded halo maps (reference conv is zero-padding -> identical math)
    for (int idx = tid; idx < 2 * HROWS * HCOLS; idx += 256) {
        const int m   = idx / (HROWS * HCOLS);
        const int rem = idx - m * (HROWS * HCOLS);
        const int r   = rem / HCOLS;
        const int j   = rem - r * HCOLS;
        const int ih  = row0 - 3 + r;
        const int iw  = j - 3;
        float v = 0.f;
        if (ih >= 0 && ih < H && iw >= 0 && iw < W)
            v = (m == 0 ? cmax : cmean)[b * HW + ih * W + iw];
        sm[m][r][j] = v;
    }
    __syncthreads();

    // --- Phase B: conv + bias + sigmoid for this band's 224 pixels ---
    if (tid < BAND * W) {
        const int dr  = tid / W;
        const int col = tid - dr * W;
        float acc = s_red[0] + s_red[1] + s_red[2] + s_red[3]
                  + proj_b[0] + conv_b[0];
        #pragma unroll
        for (int kh = 0; kh < 7; ++kh) {
            #pragma unroll
            for (int kw = 0; kw < 7; ++kw) {
                acc = fmaf(sm[0][dr + kh][col + kw], s_w[kh * 7 + kw],
                      fmaf(sm[1][dr + kh][col + kw], s_w[49 + kh * 7 + kw], acc));
            }
        }
        s_scale[tid] = 1.0f / (1.0f + __expf(-acc));
    }
    __syncthreads();

    // --- Phase C: out = x * scale for 64 channels x 4 rows (56 float4/ch) ---
    const floatx4* s4 = (const floatx4*)s_scale;   // 56 entries
    const size_t base = (size_t)(b * C + cg * CG) * HW4 + band * (BAND * W / 4);
    #pragma unroll 2
    for (int i = tid; i < CG * (BAND * W / 4); i += 256) {   // 3584 = 14 iters
        const int cl = i / 56;                // channel within group
        const int f  = i - cl * 56;           // float4 within band
        const size_t g = base + (size_t)cl * HW4 + f;
        floatx4 xv = __builtin_nontemporal_load(&x4[g]);
        floatx4 ov = xv * s4[f];
        __builtin_nontemporal_store(ov, &out4[g]);
    }
}

extern "C" void kernel_launch(void* const* d_in, const int* in_sizes, int n_in,
                              void* d_out, int out_size, void* d_ws, size_t ws_size,
                              hipStream_t stream) {
    const float* x       = (const float*)d_in[0];
    const float* keyword = (const float*)d_in[1];
    const float* conv_w  = (const float*)d_in[2];
    const float* conv_b  = (const float*)d_in[3];
    const float* proj_w  = (const float*)d_in[4];
    const float* proj_b  = (const float*)d_in[5];
    float* out = (float*)d_out;

    float* ws    = (float*)d_ws;
    float* cmax  = ws;                 // B*HW floats
    float* cmean = ws + B * HW;        // B*HW floats

    // 1) pooling: unchanged
    pool_kernel<<<(B * HW4) / 32, 512, 0, stream>>>(x, cmax, cmean);
    // 2) fused bias + conv + sigmoid + scale
    fused_kernel<<<B * NBAND * NCG, 256, 0, stream>>>(
        cmax, cmean, conv_w, conv_b, keyword, proj_w, proj_b,
        (const floatx4*)x, (floatx4*)out);
}